// Round 10
// baseline (449.566 us; speedup 1.0000x reference)
//
#include <hip/hip_runtime.h>
#include <hip/hip_bf16.h>

#define BSZ 8
#define SEQ 8192
#define DIM 128
#define NCH 128   // chunks per sequence
#define CLEN 64   // tokens per chunk

typedef unsigned short u16;
typedef unsigned int u32;
typedef short bf16x8 __attribute__((ext_vector_type(8)));
typedef float f32x4  __attribute__((ext_vector_type(4)));

__device__ __forceinline__ float us2f(u16 w){ union{u32 i;float f;}u; u.i=((u32)w)<<16; return u.f; }
__device__ __forceinline__ u16 f2us(float f){
  __hip_bfloat16 h = __float2bfloat16(f);
  union{ __hip_bfloat16 b; u16 s; }u; u.b=h; return u.s;
}
__device__ __forceinline__ float wred64(float v){
  #pragma unroll
  for (int o=1;o<64;o<<=1) v += __shfl_xor(v,o,64);
  return v;
}
__device__ __forceinline__ float red16(float v){
  v += __shfl_xor(v,1,64); v += __shfl_xor(v,2,64);
  v += __shfl_xor(v,4,64); v += __shfl_xor(v,8,64);
  return v;
}
__device__ __forceinline__ float sigmoidf_(float z){ return 1.f/(1.f+__expf(-z)); }
__device__ __forceinline__ float gelu_tanh(float x){
  float y = 0.7978845608028654f * fmaf(0.044715f*x, x*x, x);
  float e = __expf(2.f*y);
  float th = 1.f - 2.f/(e+1.f);
  return 0.5f*x*(1.f+th);
}

// ------------------- K0: weight transposes fp32->bf16 [N][K]  +  affine scalars
__global__ __launch_bounds__(256) void k_prep(
    const float* __restrict__ c,
    const float* a0,const float* a1,const float* a2,const float* a3,const float* a4,const float* a5,
    const float* s0,const float* s1,const float* s2,const float* s3,const float* s4,const float* s5,
    const float* __restrict__ w1, const float* __restrict__ w2, const float* __restrict__ wo,
    const float* __restrict__ win, const float* __restrict__ wi, const float* __restrict__ wr,
    u16* __restrict__ w1t, u16* __restrict__ w2t, u16* __restrict__ wot,
    u16* __restrict__ wint, u16* __restrict__ wit, u16* __restrict__ wrt,
    float* __restrict__ aff)
{
  const int bx = blockIdx.x;
  if (bx == 256){
    if (threadIdx.x < 64){
      const float* ws[6]={a0,a1,a2,a3,a4,a5};
      const float* bs[6]={s0,s1,s2,s3,s4,s5};
      int l = threadIdx.x;
      for (int b=0;b<BSZ;++b){
        #pragma unroll
        for (int h=0;h<6;++h){
          float v = c[b*128+l]*ws[h][l] + c[b*128+64+l]*ws[h][64+l];
          v = wred64(v);
          if (l==0) aff[b*6+h] = v + bs[h][0];
        }
      }
    }
    return;
  }
  int i = bx*256 + threadIdx.x;                  // 65536 workers
  { int n=i>>7, k=i&127; w1t[i] = f2us(w1[k*512+n]); }
  { int n=i>>9, k=i&511; w2t[i] = f2us(w2[k*128+n]); }
  if (i < 32768){ int n=i>>8, k=i&255; wot[i] = f2us(wo[k*128+n]); }
  if (i < 16384){
    int n=i>>7, k=i&127;
    wint[i] = f2us(win[k*128+n]);
    wit[i]  = f2us(wi[k*128+n]);
    wrt[i]  = f2us(wr[k*128+n]);
  }
}

// -------------------- K1: LN + MFMA gates (B direct from global) -> packed a,b + summaries
__global__ __launch_bounds__(256,3) void k_pre(
    const float* __restrict__ xg, const u16* __restrict__ wint, const float* __restrict__ b_in,
    const float* __restrict__ pos, const u16* __restrict__ wit, const float* __restrict__ b_i,
    const u16* __restrict__ wrt, const float* __restrict__ b_r, const float* __restrict__ avec,
    const float* __restrict__ aff,
    u32* __restrict__ abg,
    float* __restrict__ Ag, float* __restrict__ Bfg, float* __restrict__ Bbg)
{
  __shared__ u16 A_l[CLEN*136];   // 17408 B: lnh, then u (A-operand layout)
  __shared__ u32 abp[CLEN*132];   // 33792 B: packed (a | b<<16)
  const int t  = threadIdx.x;
  const int b  = blockIdx.x >> 7;
  const int ck = blockIdx.x & (NCH-1);
  const size_t base = ((size_t)(b*SEQ + ck*CLEN))*DIM;
  const int lane=t&63, wv=t>>6, col=lane&15, quad=lane>>4;
  const int m0 = wv*16;

  // LN
  {
    const float s1p = 1.f + aff[b*6+0];
    const int ln = lane;
    for (int i=0;i<16;++i){
      int r = m0 + i;
      float2 v = *(const float2*)(xg + base + (size_t)r*DIM + 2*ln);
      float m  = wred64(v.x+v.y)*(1.f/128.f);
      float d0=v.x-m, d1=v.y-m;
      float var = wred64(d0*d0+d1*d1)*(1.f/128.f);
      float rs = rsqrtf(var + 1e-6f);
      float vz = var*rs*rs;
      float tt2 = s1p*rsqrtf(fmaf(s1p*s1p, vz, 1e-6f));
      float sc = rs*tt2;
      *(u32*)&A_l[r*136 + 2*ln] = (u32)f2us(d0*sc) | ((u32)f2us(d1*sc)<<16);
    }
  }
  __syncthreads();   // LN writes -> mm reads

  // ---- mm B: u = lnh @ w_in  (B direct from global, L2-hot) ----
  f32x4 uacc[8];
  #pragma unroll
  for (int n=0;n<8;++n) uacc[n]=(f32x4){0.f,0.f,0.f,0.f};
  #pragma unroll
  for (int c=0;c<2;++c){
    #pragma unroll
    for (int k2=0;k2<2;++k2){
      bf16x8 av = *(const bf16x8*)&A_l[(m0+col)*136 + c*64 + k2*32 + quad*8];
      #pragma unroll
      for (int n=0;n<8;++n){
        bf16x8 bv = *(const bf16x8*)&wint[(size_t)(n*16+col)*128 + c*64 + k2*32 + quad*8];
        uacc[n] = __builtin_amdgcn_mfma_f32_16x16x32_bf16(av, bv, uacc[n], 0,0,0);
      }
    }
  }
  float u_c[8][4];
  #pragma unroll
  for (int n=0;n<8;++n){
    int nc = n*16 + col;
    float bi = b_in[nc];
    #pragma unroll
    for (int r=0;r<4;++r){
      int row = m0 + quad*4 + r;
      u_c[n][r] = uacc[n][r] + bi + pos[(size_t)(ck*CLEN+row)*DIM + nc];
    }
  }
  __syncthreads();   // all lnh reads done before u overwrites A_l

  // write u (bf16) into A_l
  #pragma unroll
  for (int n=0;n<8;++n){
    #pragma unroll
    for (int r=0;r<4;++r)
      A_l[(m0+quad*4+r)*136 + n*16+col] = f2us(u_c[n][r]);
  }
  __syncthreads();   // u writes -> mm reads

  // ---- mm C: gi = sigmoid(u @ w_i + b_i) ----
  f32x4 gacc[8];
  #pragma unroll
  for (int n=0;n<8;++n) gacc[n]=(f32x4){0.f,0.f,0.f,0.f};
  #pragma unroll
  for (int c=0;c<2;++c){
    #pragma unroll
    for (int k2=0;k2<2;++k2){
      bf16x8 av = *(const bf16x8*)&A_l[(m0+col)*136 + c*64 + k2*32 + quad*8];
      #pragma unroll
      for (int n=0;n<8;++n){
        bf16x8 bv = *(const bf16x8*)&wit[(size_t)(n*16+col)*128 + c*64 + k2*32 + quad*8];
        gacc[n] = __builtin_amdgcn_mfma_f32_16x16x32_bf16(av, bv, gacc[n], 0,0,0);
      }
    }
  }
  float gi_c[8][4];
  #pragma unroll
  for (int n=0;n<8;++n){
    float bi = b_i[n*16+col];
    #pragma unroll
    for (int r=0;r<4;++r) gi_c[n][r] = sigmoidf_(gacc[n][r]+bi);
  }

  // ---- mm D: gr ----  (A_l unchanged; no barrier needed)
  f32x4 racc[8];
  #pragma unroll
  for (int n=0;n<8;++n) racc[n]=(f32x4){0.f,0.f,0.f,0.f};
  #pragma unroll
  for (int c=0;c<2;++c){
    #pragma unroll
    for (int k2=0;k2<2;++k2){
      bf16x8 av = *(const bf16x8*)&A_l[(m0+col)*136 + c*64 + k2*32 + quad*8];
      #pragma unroll
      for (int n=0;n<8;++n){
        bf16x8 bv = *(const bf16x8*)&wrt[(size_t)(n*16+col)*128 + c*64 + k2*32 + quad*8];
        racc[n] = __builtin_amdgcn_mfma_f32_16x16x32_bf16(av, bv, racc[n], 0,0,0);
      }
    }
  }

  // a_t, b_t -> packed LDS + packed global
  #pragma unroll
  for (int n=0;n<8;++n){
    int nc = n*16 + col;
    float la = __logf(avec[nc]);
    float br = b_r[nc];
    #pragma unroll
    for (int r=0;r<4;++r){
      int row = m0 + quad*4 + r;
      float g = sigmoidf_(racc[n][r]+br);
      float a = __expf(8.f*g*la);
      float bb = sqrtf(fmaxf(1.f-a*a,0.f))*gi_c[n][r]*u_c[n][r];
      u32 pk = (u32)f2us(a) | ((u32)f2us(bb)<<16);
      abp[row*132+nc] = pk;
      abg[base + (size_t)row*DIM + nc] = pk;
    }
  }
  __syncthreads();   // abp writes -> summary reads

  const int sbase = (b*NCH+ck)*DIM;
  if (t < 128){
    float h=0.f, p=1.f;
    #pragma unroll 4
    for (int tt=0;tt<CLEN;++tt){
      u32 v=abp[tt*132+t];
      float a=us2f((u16)v), bb=us2f((u16)(v>>16));
      h=fmaf(a,h,bb); p*=a;
    }
    Ag[sbase+t]=p; Bfg[sbase+t]=h;
  } else {
    int ch=t-128; float h=0.f;
    #pragma unroll 4
    for (int tt=CLEN-1;tt>=0;--tt){
      u32 v=abp[tt*132+ch];
      h=fmaf(us2f((u16)v),h,us2f((u16)(v>>16)));
    }
    Bbg[sbase+ch]=h;
  }
}

// ------------------------------------------------ K2: prefix over chunk summaries
__global__ __launch_bounds__(128) void k_chunkscan(
    const float* __restrict__ Ag, const float* __restrict__ Bfg, const float* __restrict__ Bbg,
    float* __restrict__ Hf, float* __restrict__ Hb)
{
  const int dir = blockIdx.x >> 3, b = blockIdx.x & 7, ch = threadIdx.x;
  float s = 0.f;
  if (dir==0){
    for (int c=0;c<NCH;++c){ size_t i=((size_t)(b*NCH+c))*DIM+ch; Hf[i]=s; s=fmaf(Ag[i],s,Bfg[i]); }
  } else {
    for (int c=NCH-1;c>=0;--c){ size_t i=((size_t)(b*NCH+c))*DIM+ch; Hb[i]=s; s=fmaf(Ag[i],s,Bbg[i]); }
  }
}

// ---- K3 fused: seeded scan -> MFMA out-proj -> x1 (regs) -> LN2 -> MLP -> out
__global__ __launch_bounds__(256,3) void k_scanmlp(
    const u32* __restrict__ abg, const float* __restrict__ Hf, const float* __restrict__ Hb,
    const float* __restrict__ xg, const u16* __restrict__ wot, const float* __restrict__ b_out,
    const u16* __restrict__ w1t, const float* __restrict__ b1v,
    const u16* __restrict__ w2t, const float* __restrict__ b2v,
    const float* __restrict__ aff, float* __restrict__ outg)
{
  __shared__ u16 ubuf[2*CLEN*136];     // 34816 B
  u16* hcat = ubuf;                    // [64][264] during scan/out-proj
  u16* h2l  = ubuf;                    // [64][136] after repurpose
  u16* m1p  = ubuf + CLEN*136;         // [64][136]
  const int t  = threadIdx.x;
  const int b  = blockIdx.x >> 7;
  const int ck = blockIdx.x & (NCH-1);
  const size_t base = ((size_t)(b*SEQ + ck*CLEN))*DIM;
  const int lane=t&63, wv=t>>6, col=lane&15, quad=lane>>4;
  const int m0 = wv*16;

  // phase 1: seeded scans
  const int pbase=(b*NCH+ck)*DIM;
  if (t<128){
    float h=Hf[pbase+t];
    #pragma unroll 4
    for (int tt=0;tt<CLEN;++tt){
      u32 v = abg[base + (size_t)tt*DIM + t];
      h=fmaf(us2f((u16)v),h,us2f((u16)(v>>16)));
      hcat[tt*264+t]=f2us(h);
    }
  } else {
    int ch=t-128;
    float h=Hb[pbase+ch];
    #pragma unroll 4
    for (int tt=CLEN-1;tt>=0;--tt){
      u32 v = abg[base + (size_t)tt*DIM + ch];
      h=fmaf(us2f((u16)v),h,us2f((u16)(v>>16)));
      hcat[tt*264+128+ch]=f2us(h);
    }
  }
  __syncthreads();   // hcat complete

  // phase 2: out-proj
  f32x4 acc[8];
  #pragma unroll
  for (int n=0;n<8;++n) acc[n]=(f32x4){0.f,0.f,0.f,0.f};
  #pragma unroll
  for (int chk=0; chk<4; ++chk){
    #pragma unroll
    for (int k2=0;k2<2;++k2){
      bf16x8 av = *(const bf16x8*)&hcat[(m0+col)*264 + chk*64 + k2*32 + quad*8];
      #pragma unroll
      for (int n=0;n<8;++n){
        bf16x8 bv = *(const bf16x8*)&wot[(size_t)(n*16+col)*256 + chk*64 + k2*32 + quad*8];
        acc[n] = __builtin_amdgcn_mfma_f32_16x16x32_bf16(av, bv, acc[n], 0,0,0);
      }
    }
  }
  const float g1=aff[b*6+2];
  float x1r[8][4];
  #pragma unroll
  for (int n=0;n<8;++n){
    int nc = n*16 + col;
    float bo = b_out[nc];
    #pragma unroll
    for (int r=0;r<4;++r){
      int row = m0 + quad*4 + r;
      x1r[n][r] = fmaf(g1, acc[n][r]+bo, xg[base + (size_t)row*DIM + nc]);
    }
  }
  __syncthreads();   // hcat reads done; ubuf repurposed

  // phase 3: LN2 -> h2l
  const float s2p=1.f+aff[b*6+3], b2a=aff[b*6+4], g2=aff[b*6+5];
  #pragma unroll
  for (int r=0;r<4;++r){
    float s=0.f;
    #pragma unroll
    for (int n=0;n<8;++n) s+=x1r[n][r];
    s=red16(s); float m=s*(1.f/128.f);
    float q2=0.f;
    #pragma unroll
    for (int n=0;n<8;++n){ float d=x1r[n][r]-m; q2+=d*d; }
    q2=red16(q2); float rs=rsqrtf(q2*(1.f/128.f)+1e-6f);
    #pragma unroll
    for (int n=0;n<8;++n)
      h2l[(m0+quad*4+r)*136 + n*16+col] = f2us(fmaf((x1r[n][r]-m)*rs, s2p, b2a));
  }
  __syncthreads();   // h2l writes -> mm1 reads

  // phase 4: MLP
  f32x4 acc2[8];
  #pragma unroll
  for (int n=0;n<8;++n) acc2[n]=(f32x4){0.f,0.f,0.f,0.f};
  for (int p=0;p<4;++p){
    f32x4 accp[8];
    #pragma unroll
    for (int n=0;n<8;++n) accp[n]=(f32x4){0.f,0.f,0.f,0.f};
    #pragma unroll
    for (int c=0;c<2;++c){
      #pragma unroll
      for (int k2=0;k2<2;++k2){
        bf16x8 av = *(const bf16x8*)&h2l[(m0+col)*136 + c*64 + k2*32 + quad*8];
        #pragma unroll
        for (int n=0;n<8;++n){
          bf16x8 bv = *(const bf16x8*)&w1t[(size_t)(p*128+n*16+col)*128 + c*64 + k2*32 + quad*8];
          accp[n] = __builtin_amdgcn_mfma_f32_16x16x32_bf16(av, bv, accp[n], 0,0,0);
        }
      }
    }
    __syncthreads();   // previous iter's m1p reads done before overwrite
    #pragma unroll
    for (int n=0;n<8;++n){
      int nc = n*16 + col;
      float bb = b1v[p*128 + nc];
      #pragma unroll
      for (int r=0;r<4;++r)
        m1p[(m0+quad*4+r)*136 + nc] = f2us(gelu_tanh(accp[n][r] + bb));
    }
    __syncthreads();   // m1p writes -> mm2 reads
    #pragma unroll
    for (int c=0;c<2;++c){
      #pragma unroll
      for (int k2=0;k2<2;++k2){
        bf16x8 av = *(const bf16x8*)&m1p[(m0+col)*136 + c*64 + k2*32 + quad*8];
        #pragma unroll
        for (int n=0;n<8;++n){
          bf16x8 bv = *(const bf16x8*)&w2t[(size_t)(n*16+col)*512 + p*128 + c*64 + k2*32 + quad*8];
          acc2[n] = __builtin_amdgcn_mfma_f32_16x16x32_bf16(av, bv, acc2[n], 0,0,0);
        }
      }
    }
  }
  // epilogue
  #pragma unroll
  for (int n=0;n<8;++n){
    int nc = n*16 + col;
    float bb = b2v[nc];
    #pragma unroll
    for (int r=0;r<4;++r){
      int row = m0 + quad*4 + r;
      outg[base + (size_t)row*DIM + nc] = fmaf(g2, acc2[n][r] + bb, x1r[n][r]);
    }
  }
}

// ----------------------------------------------------------------------------
extern "C" void kernel_launch(void* const* d_in, const int* in_sizes, int n_in,
                              void* d_out, int out_size, void* d_ws, size_t ws_size,
                              hipStream_t stream)
{
  (void)in_sizes; (void)n_in; (void)out_size; (void)ws_size;
  const float* x   =(const float*)d_in[0];
  const float* c   =(const float*)d_in[1];
  const float* c1sw=(const float*)d_in[2];  const float* c1sb=(const float*)d_in[3];
  const float* c1bw=(const float*)d_in[4];  const float* c1bb=(const float*)d_in[5];
  const float* g1w =(const float*)d_in[6];  const float* g1b =(const float*)d_in[7];
  const float* win =(const float*)d_in[8];  const float* binv=(const float*)d_in[9];
  const float* pos =(const float*)d_in[10];
  const float* wi  =(const float*)d_in[11]; const float* biv =(const float*)d_in[12];
  const float* wr  =(const float*)d_in[13]; const float* brv =(const float*)d_in[14];
  const float* av  =(const float*)d_in[15];
  const float* wout=(const float*)d_in[16]; const float* bout=(const float*)d_in[17];
  const float* c2sw=(const float*)d_in[18]; const float* c2sb=(const float*)d_in[19];
  const float* c2bw=(const float*)d_in[20]; const float* c2bb=(const float*)d_in[21];
  const float* g2w =(const float*)d_in[22]; const float* g2b =(const float*)d_in[23];
  const float* w1  =(const float*)d_in[24]; const float* b1v =(const float*)d_in[25];
  const float* w2  =(const float*)d_in[26]; const float* b2v =(const float*)d_in[27];

  float* wsf  = (float*)d_ws;
  float* Ag   = wsf;
  float* Bfg  = Ag   + 131072;
  float* Bbg  = Bfg  + 131072;
  float* Hf   = Bbg  + 131072;
  float* Hb   = Hf   + 131072;
  float* aff  = Hb   + 131072;       // 48 (pad 64)
  u16*   w1t  = (u16*)(aff + 64);    // [512][128]
  u16*   w2t  = w1t + 65536;         // [128][512]
  u16*   wot  = w2t + 65536;         // [128][256]
  u16*   wint = wot + 32768;         // [128][128]
  u16*   wit  = wint + 16384;
  u16*   wrt  = wit  + 16384;
  u32*   abg  = (u32*)(wrt + 16384); // [BSZ*SEQ*DIM] packed bf16 pair

  float* outg = (float*)d_out;

  k_prep<<<dim3(257),dim3(256),0,stream>>>(c, c1sw,c1bw,g1w,c2sw,c2bw,g2w,
                                           c1sb,c1bb,g1b,c2sb,c2bb,g2b,
                                           w1,w2,wout,win,wi,wr,
                                           w1t,w2t,wot,wint,wit,wrt, aff);
  k_pre<<<dim3(BSZ*NCH),dim3(256),0,stream>>>(x,wint,binv,pos,wit,biv,wrt,brv,av,aff,
                                              abg, Ag,Bfg,Bbg);
  k_chunkscan<<<dim3(16),dim3(128),0,stream>>>(Ag,Bfg,Bbg,Hf,Hb);
  k_scanmlp<<<dim3(BSZ*NCH),dim3(256),0,stream>>>(abg,Hf,Hb,x,wot,bout,
                                                  w1t,b1v,w2t,b2v,aff,outg);
}